// Round 1
// baseline (185.606 us; speedup 1.0000x reference)
//
#include <hip/hip_runtime.h>

#define RES 128
#define FEAT 8

__global__ __launch_bounds__(256) void trilerp_kernel(
    const float* __restrict__ pts,
    const float* __restrict__ features,
    float* __restrict__ out,
    int npts)
{
    int i = blockIdx.x * blockDim.x + threadIdx.x;
    if (i >= npts) return;

    float px = pts[3 * i + 0];
    float py = pts[3 * i + 1];
    float pz = pts[3 * i + 2];

    // x = ((p + 1) * 0.5) * (RES - 1), matching reference op order
    float x = (px + 1.0f) * 0.5f * (float)(RES - 1);
    float y = (py + 1.0f) * 0.5f * (float)(RES - 1);
    float z = (pz + 1.0f) * 0.5f * (float)(RES - 1);

    float fx0 = fminf(fmaxf(floorf(x), 0.0f), (float)(RES - 2));
    float fy0 = fminf(fmaxf(floorf(y), 0.0f), (float)(RES - 2));
    float fz0 = fminf(fmaxf(floorf(z), 0.0f), (float)(RES - 2));

    int ix = (int)fx0, iy = (int)fy0, iz = (int)fz0;
    float fx = x - fx0, fy = y - fy0, fz = z - fz0;

    float wx[2] = {1.0f - fx, fx};
    float wy[2] = {1.0f - fy, fy};
    float wz[2] = {1.0f - fz, fz};

    float acc[FEAT];
#pragma unroll
    for (int k = 0; k < FEAT; ++k) acc[k] = 0.0f;

    int base = (ix * RES + iy) * RES + iz;

#pragma unroll
    for (int dx = 0; dx < 2; ++dx) {
#pragma unroll
        for (int dy = 0; dy < 2; ++dy) {
#pragma unroll
            for (int dz = 0; dz < 2; ++dz) {
                int idx = base + dx * (RES * RES) + dy * RES + dz;
                float w = wx[dx] * wy[dy] * wz[dz];
                const float4* fp =
                    reinterpret_cast<const float4*>(features + (size_t)idx * FEAT);
                float4 a = fp[0];
                float4 b = fp[1];
                acc[0] += w * a.x; acc[1] += w * a.y;
                acc[2] += w * a.z; acc[3] += w * a.w;
                acc[4] += w * b.x; acc[5] += w * b.y;
                acc[6] += w * b.z; acc[7] += w * b.w;
            }
        }
    }

    float4* op = reinterpret_cast<float4*>(out + (size_t)i * FEAT);
    op[0] = make_float4(acc[0], acc[1], acc[2], acc[3]);
    op[1] = make_float4(acc[4], acc[5], acc[6], acc[7]);
}

extern "C" void kernel_launch(void* const* d_in, const int* in_sizes, int n_in,
                              void* d_out, int out_size, void* d_ws, size_t ws_size,
                              hipStream_t stream) {
    const float* pts = (const float*)d_in[0];
    const float* features = (const float*)d_in[1];
    float* out = (float*)d_out;
    int npts = in_sizes[0] / 3;

    int block = 256;
    int grid = (npts + block - 1) / block;
    trilerp_kernel<<<grid, block, 0, stream>>>(pts, features, out, npts);
}